// Round 7
// baseline (669.029 us; speedup 1.0000x reference)
//
#include <hip/hip_runtime.h>
#include <cstdint>

#define NQ    8192
#define NNEG  16384
#define DIM   128
#define SPLIT 16
#define CHUNK (NNEG / SPLIT)          // 1024
// (1/TAU) * log2(e): MFMA output is directly the base-2 exponent
#define K_SCALE 7.2134752044448169f
#define LN2     0.69314718055994531f
// Schraudolph exp2: exp2(x) ~= bitcast<float>( (int)(x*2^23 + 127*2^23) )
// exact at integer x (incl. x=0, the dominant softmax term); error in [0, +6.1%)
// on fractional x -- negligible vs fp8 score noise. Clamp to 0 for x <= -127.
#define EXP_C 8388608.0f              // 2^23
#define EXP_B 1065353216.0f           // 127 * 2^23 (bit pattern of 1.0f)

typedef __attribute__((ext_vector_type(8))) int   i32x8;
typedef __attribute__((ext_vector_type(4))) float f32x4;

union U8 { i32x8 v; int4 h[2]; };

__device__ inline float waveReduceSum(float v) {
#pragma unroll
    for (int m = 32; m >= 1; m >>= 1) v += __shfl_xor(v, m, 64);
    return v;
}

// fast exp2 for x <= ~0 (flushes to 0 below -127); 3 full-rate VALU ops, no trans.
// t = EXP_B - EXP_C*nm must be precomputed by caller; computes exp2(y - nm).
__device__ inline float fexp2(float y, float t) {
    float v = fmaxf(fmaf(y, EXP_C, t), 0.0f);
    return __int_as_float((int)v);
}

// ---------------- kernel 1: f32 -> fp8 e4m3 convert + fused positive-logit dot ----
__global__ __launch_bounds__(256) void iw_prep(
    const float* __restrict__ q, const float* __restrict__ p,
    const float* __restrict__ neg,
    unsigned char* __restrict__ qb8, unsigned char* __restrict__ nb8,
    float* __restrict__ out)
{
    const int tid = threadIdx.x;
    const int t = blockIdx.x * 256 + tid;
    constexpr int QT = NQ * DIM / 8;      // 131072 q-threads
    if (t < QT) {
        const float4* q4 = (const float4*)q;
        float4 v0 = q4[t * 2], v1 = q4[t * 2 + 1];
        int w0 = __builtin_amdgcn_cvt_pk_fp8_f32(v0.x * K_SCALE, v0.y * K_SCALE, 0, false);
        w0     = __builtin_amdgcn_cvt_pk_fp8_f32(v0.z * K_SCALE, v0.w * K_SCALE, w0, true);
        int w1 = __builtin_amdgcn_cvt_pk_fp8_f32(v1.x * K_SCALE, v1.y * K_SCALE, 0, false);
        w1     = __builtin_amdgcn_cvt_pk_fp8_f32(v1.z * K_SCALE, v1.w * K_SCALE, w1, true);
        ((int2*)qb8)[t] = make_int2(w0, w1);
        // fused pos logit: q . pos (raw f32)
        const float4* p4 = (const float4*)p;
        float4 p0 = p4[t * 2], p1 = p4[t * 2 + 1];
        float acc = fmaf(v0.x, p0.x, fmaf(v0.y, p0.y, fmaf(v0.z, p0.z, v0.w * p0.w)));
        acc = fmaf(v1.x, p1.x, fmaf(v1.y, p1.y, fmaf(v1.z, p1.z, fmaf(v1.w, p1.w, acc))));
        acc = waveReduceSum(acc);
        __shared__ float red[4];
        if ((tid & 63) == 0) red[tid >> 6] = acc;
        __syncthreads();
        if (tid == 0) {
            float s = red[0] + red[1] + red[2] + red[3];
            atomicAdd(out, s * (-1.0f / (0.2f * (float)NQ)));
        }
    } else {
        int j = t - QT;                   // < 262144
        const float4* n4 = (const float4*)neg;
        float4 v0 = n4[j * 2], v1 = n4[j * 2 + 1];
        int w0 = __builtin_amdgcn_cvt_pk_fp8_f32(v0.x, v0.y, 0, false);
        w0     = __builtin_amdgcn_cvt_pk_fp8_f32(v0.z, v0.w, w0, true);
        int w1 = __builtin_amdgcn_cvt_pk_fp8_f32(v1.x, v1.y, 0, false);
        w1     = __builtin_amdgcn_cvt_pk_fp8_f32(v1.z, v1.w, w1, true);
        ((int2*)nb8)[j] = make_int2(w0, w1);
    }
}

// ---------------- kernel 2: flash-LSE main (MX-fp8, K=128/instr) ----------------
// grid (64, 16): blockIdx.x = row block (BM=128), blockIdx.y = neg chunk (1024)
// v8: v7's barrier-free no-LDS skeleton, occupancy-fixed. v7 at (256,3) ran only
//     2 waves/SIMD -> ~900 cyc/tile of unhidden latency (VALUBusy 36%). Here:
//     __launch_bounds__(256,4) -> 4 blocks/CU (VGPR ~100 < 128 cap, no LDS cap),
//     3 rotating B register buffers -> ~2-iteration (~1200 cyc) prefetch distance.
//     Addresses/MFMA order/LSE arithmetic bit-identical to v7.
__global__ __launch_bounds__(256, 4) void iw_main(
    const unsigned char* __restrict__ qb8, const unsigned char* __restrict__ nb8,
    float2* __restrict__ partial)
{
    constexpr int BM = 128;

    const int tid  = threadIdx.x;
    const int lane = tid & 63;
    const int w    = tid >> 6;        // wave 0..3, owns 32 query rows
    const int quad = lane >> 4;
    const int c0   = lane & 15;

    const int row0   = blockIdx.x * BM;
    const int nbase0 = blockIdx.y * CHUNK;

    // ---- A fragments straight from global (fp8 row-major; 32 B/lane = K slice) ----
    U8 afrag[2];
#pragma unroll
    for (int rs = 0; rs < 2; ++rs) {
        const int qrow = row0 + w * 32 + rs * 16 + c0;
        const int4* pa = reinterpret_cast<const int4*>(qb8 + (size_t)qrow * DIM + quad * 32);
        afrag[rs].h[0] = pa[0];
        afrag[rs].h[1] = pa[1];
    }

    // per-lane B base: neg row (nbase0 + c0), bytes quad*32; +ns*2048 adds 16 rows;
    // +8192 per tile (64 rows).
    const unsigned char* pt = nb8 + (size_t)(nbase0 + c0) * DIM + quad * 32;

    float m_s[2][4], l_s[2][4];
#pragma unroll
    for (int rs = 0; rs < 2; ++rs)
#pragma unroll
        for (int i = 0; i < 4; ++i) { m_s[rs][i] = -1e30f; l_s[rs][i] = 0.f; }

    const f32x4 zero4 = {0.f, 0.f, 0.f, 0.f};
    f32x4 acc[2][4];
    U8 b0[4], b1[4], b2[4];

#define LOADB(B, T) do {                                                    \
    const unsigned char* _pt = pt + (T) * 8192;                             \
    const int4* _p0 = reinterpret_cast<const int4*>(_pt);                   \
    (B)[0].h[0] = _p0[0]; (B)[0].h[1] = _p0[1];                             \
    const int4* _p1 = reinterpret_cast<const int4*>(_pt + 2048);            \
    (B)[1].h[0] = _p1[0]; (B)[1].h[1] = _p1[1];                             \
    const int4* _p2 = reinterpret_cast<const int4*>(_pt + 4096);            \
    (B)[2].h[0] = _p2[0]; (B)[2].h[1] = _p2[1];                             \
    const int4* _p3 = reinterpret_cast<const int4*>(_pt + 6144);            \
    (B)[3].h[0] = _p3[0]; (B)[3].h[1] = _p3[1];                             \
} while (0)

#define COMPUTE(B) do {                                                     \
    acc[0][0] = __builtin_amdgcn_mfma_scale_f32_16x16x128_f8f6f4(           \
        afrag[0].v, (B)[0].v, zero4, 0, 0, 0, 127, 0, 127);                 \
    acc[1][0] = __builtin_amdgcn_mfma_scale_f32_16x16x128_f8f6f4(           \
        afrag[1].v, (B)[0].v, zero4, 0, 0, 0, 127, 0, 127);                 \
    acc[0][1] = __builtin_amdgcn_mfma_scale_f32_16x16x128_f8f6f4(           \
        afrag[0].v, (B)[1].v, zero4, 0, 0, 0, 127, 0, 127);                 \
    acc[1][1] = __builtin_amdgcn_mfma_scale_f32_16x16x128_f8f6f4(           \
        afrag[1].v, (B)[1].v, zero4, 0, 0, 0, 127, 0, 127);                 \
    acc[0][2] = __builtin_amdgcn_mfma_scale_f32_16x16x128_f8f6f4(           \
        afrag[0].v, (B)[2].v, zero4, 0, 0, 0, 127, 0, 127);                 \
    acc[1][2] = __builtin_amdgcn_mfma_scale_f32_16x16x128_f8f6f4(           \
        afrag[1].v, (B)[2].v, zero4, 0, 0, 0, 127, 0, 127);                 \
    acc[0][3] = __builtin_amdgcn_mfma_scale_f32_16x16x128_f8f6f4(           \
        afrag[0].v, (B)[3].v, zero4, 0, 0, 0, 127, 0, 127);                 \
    acc[1][3] = __builtin_amdgcn_mfma_scale_f32_16x16x128_f8f6f4(           \
        afrag[1].v, (B)[3].v, zero4, 0, 0, 0, 127, 0, 127);                 \
} while (0)

#define LSE_UPDATE() do {                                                   \
    _Pragma("unroll")                                                       \
    for (int rs = 0; rs < 2; ++rs) {                                        \
        _Pragma("unroll")                                                   \
        for (int i = 0; i < 4; ++i) {                                       \
            float y0 = acc[rs][0][i], y1 = acc[rs][1][i];                   \
            float y2 = acc[rs][2][i], y3 = acc[rs][3][i];                   \
            float m0 = m_s[rs][i];                                          \
            float nm = fmaxf(fmaxf(fmaxf(y2, y3), m0), fmaxf(y0, y1));      \
            float tt = fmaf(nm, -EXP_C, EXP_B);                             \
            float e0 = fexp2(y0, tt), e1 = fexp2(y1, tt);                   \
            float e2 = fexp2(y2, tt), e3 = fexp2(y3, tt);                   \
            float er = fexp2(m0, tt);                                       \
            l_s[rs][i] = fmaf(l_s[rs][i], er, (e0 + e1) + (e2 + e3));       \
            m_s[rs][i] = nm;                                                \
        }                                                                   \
    }                                                                       \
} while (0)

    // prologue: tiles 0,1 in flight
    LOADB(b0, 0);
    LOADB(b1, 1);

    // steady state: period-3 rotation; load for tile t+2 issues before compute of
    // tile t -> ~2-iteration prefetch distance, no barriers, no LDS.
    // t = 0..11 (4 full triples)
#pragma unroll
    for (int p = 0; p < 4; ++p) {
        const int t3 = 3 * p;
        LOADB(b2, t3 + 2);  COMPUTE(b0); LSE_UPDATE();
        LOADB(b0, t3 + 3);  COMPUTE(b1); LSE_UPDATE();
        LOADB(b1, t3 + 4);  COMPUTE(b2); LSE_UPDATE();
    }
    // t = 12,13 (loads for tiles 14,15), then drain 14,15
    LOADB(b2, 14);  COMPUTE(b0); LSE_UPDATE();
    LOADB(b0, 15);  COMPUTE(b1); LSE_UPDATE();
    COMPUTE(b2); LSE_UPDATE();
    COMPUTE(b0); LSE_UPDATE();

#undef LOADB
#undef COMPUTE
#undef LSE_UPDATE

    // ---- merge (m,l) across the 16 lanes of each quad-row group (exact exp2) ----
#pragma unroll
    for (int rs = 0; rs < 2; ++rs) {
#pragma unroll
        for (int i = 0; i < 4; ++i) {
            float m = m_s[rs][i], l = l_s[rs][i];
#pragma unroll
            for (int s = 1; s < 16; s <<= 1) {
                float om = __shfl_xor(m, s, 64);
                float ol = __shfl_xor(l, s, 64);
                float nm = fmaxf(m, om);
                l = l * __builtin_amdgcn_exp2f(m - nm) + ol * __builtin_amdgcn_exp2f(om - nm);
                m = nm;
            }
            if (c0 == 0) {
                int grow = row0 + w * 32 + rs * 16 + quad * 4 + i;
                partial[(size_t)blockIdx.y * NQ + grow] = make_float2(m, l);
            }
        }
    }
}

// ---------------- kernel 3: merge chunks + mean reduce ----------------
__global__ __launch_bounds__(256) void iw_merge(
    const float2* __restrict__ partial, float* __restrict__ out)
{
    const int tid = threadIdx.x;
    const int row = blockIdx.x * 256 + tid;   // 32 blocks * 256 = 8192
    float M = -1e30f, L = 0.f;
#pragma unroll
    for (int c = 0; c < SPLIT; ++c) {
        float2 p = partial[(size_t)c * NQ + row];
        float nm = fmaxf(M, p.x);
        L = L * __builtin_amdgcn_exp2f(M - nm) + p.y * __builtin_amdgcn_exp2f(p.x - nm);
        M = nm;
    }
    float lse = LN2 * (M + __log2f(L));       // natural-log LSE of scores/tau
    float v = lse * (1.0f / (float)NQ);
    v = waveReduceSum(v);
    __shared__ float red[4];
    if ((tid & 63) == 0) red[tid >> 6] = v;
    __syncthreads();
    if (tid == 0) atomicAdd(out, red[0] + red[1] + red[2] + red[3]);
}

// ---------------- launch ----------------
extern "C" void kernel_launch(void* const* d_in, const int* in_sizes, int n_in,
                              void* d_out, int out_size, void* d_ws, size_t ws_size,
                              hipStream_t stream) {
    const float* q   = (const float*)d_in[0];
    const float* pos = (const float*)d_in[1];
    const float* neg = (const float*)d_in[2];
    float* out = (float*)d_out;

    unsigned char* qb8 = (unsigned char*)d_ws;                     // 1 MB
    unsigned char* nb8 = qb8 + (size_t)NQ * DIM;                   // 2 MB
    float2* partial    = (float2*)(nb8 + (size_t)NNEG * DIM);      // 1 MB

    hipMemsetAsync(out, 0, sizeof(float), stream);
    iw_prep <<<1536, 256, 0, stream>>>(q, pos, neg, qb8, nb8, out);
    iw_main <<<dim3(NQ / 128, SPLIT), 256, 0, stream>>>(qb8, nb8, partial);
    iw_merge<<<32,   256, 0, stream>>>(partial, out);
}

// Round 8
// 111.404 us; speedup vs baseline: 6.0054x; 6.0054x over previous
//
#include <hip/hip_runtime.h>
#include <cstdint>

#define NQ    8192
#define NNEG  16384
#define DIM   128
#define SPLIT 16
#define CHUNK (NNEG / SPLIT)          // 1024
// (1/TAU) * log2(e): MFMA output is directly the base-2 exponent
#define K_SCALE 7.2134752044448169f
#define LN2     0.69314718055994531f
// Schraudolph exp2: exp2(x) ~= bitcast<float>( (int)(x*2^23 + 127*2^23) )
// exact at integer x (incl. x=0, the dominant softmax term); error in [0, +6.1%)
// on fractional x -- negligible vs fp8 score noise. Clamp to 0 for x <= -127.
#define EXP_C 8388608.0f              // 2^23
#define EXP_B 1065353216.0f           // 127 * 2^23 (bit pattern of 1.0f)

typedef __attribute__((ext_vector_type(8))) int   i32x8;
typedef __attribute__((ext_vector_type(4))) float f32x4;

union U8 { i32x8 v; int4 h[2]; };

__device__ inline void async_load16(const void* g, void* l) {
    __builtin_amdgcn_global_load_lds(
        (const __attribute__((address_space(1))) void*)g,
        (__attribute__((address_space(3))) void*)l, 16, 0, 0);
}

__device__ inline float waveReduceSum(float v) {
#pragma unroll
    for (int m = 32; m >= 1; m >>= 1) v += __shfl_xor(v, m, 64);
    return v;
}

// fast exp2 for x <= ~0 (flushes to 0 below -127); 3 full-rate VALU ops, no trans.
// t = EXP_B - EXP_C*nm must be precomputed by caller; computes exp2(y - nm).
__device__ inline float fexp2(float y, float t) {
    float v = fmaxf(fmaf(y, EXP_C, t), 0.0f);
    return __int_as_float((int)v);
}

// ---------------- kernel 1: f32 -> fp8 e4m3 convert + fused positive-logit dot ----
__global__ __launch_bounds__(256) void iw_prep(
    const float* __restrict__ q, const float* __restrict__ p,
    const float* __restrict__ neg,
    unsigned char* __restrict__ qb8, unsigned char* __restrict__ nb8,
    float* __restrict__ out)
{
    const int tid = threadIdx.x;
    const int t = blockIdx.x * 256 + tid;
    constexpr int QT = NQ * DIM / 8;      // 131072 q-threads
    if (t < QT) {
        const float4* q4 = (const float4*)q;
        float4 v0 = q4[t * 2], v1 = q4[t * 2 + 1];
        int w0 = __builtin_amdgcn_cvt_pk_fp8_f32(v0.x * K_SCALE, v0.y * K_SCALE, 0, false);
        w0     = __builtin_amdgcn_cvt_pk_fp8_f32(v0.z * K_SCALE, v0.w * K_SCALE, w0, true);
        int w1 = __builtin_amdgcn_cvt_pk_fp8_f32(v1.x * K_SCALE, v1.y * K_SCALE, 0, false);
        w1     = __builtin_amdgcn_cvt_pk_fp8_f32(v1.z * K_SCALE, v1.w * K_SCALE, w1, true);
        ((int2*)qb8)[t] = make_int2(w0, w1);
        // fused pos logit: q . pos (raw f32)
        const float4* p4 = (const float4*)p;
        float4 p0 = p4[t * 2], p1 = p4[t * 2 + 1];
        float acc = fmaf(v0.x, p0.x, fmaf(v0.y, p0.y, fmaf(v0.z, p0.z, v0.w * p0.w)));
        acc = fmaf(v1.x, p1.x, fmaf(v1.y, p1.y, fmaf(v1.z, p1.z, fmaf(v1.w, p1.w, acc))));
        acc = waveReduceSum(acc);
        __shared__ float red[4];
        if ((tid & 63) == 0) red[tid >> 6] = acc;
        __syncthreads();
        if (tid == 0) {
            float s = red[0] + red[1] + red[2] + red[3];
            atomicAdd(out, s * (-1.0f / (0.2f * (float)NQ)));
        }
    } else {
        int j = t - QT;                   // < 262144
        const float4* n4 = (const float4*)neg;
        float4 v0 = n4[j * 2], v1 = n4[j * 2 + 1];
        int w0 = __builtin_amdgcn_cvt_pk_fp8_f32(v0.x, v0.y, 0, false);
        w0     = __builtin_amdgcn_cvt_pk_fp8_f32(v0.z, v0.w, w0, true);
        int w1 = __builtin_amdgcn_cvt_pk_fp8_f32(v1.x, v1.y, 0, false);
        w1     = __builtin_amdgcn_cvt_pk_fp8_f32(v1.z, v1.w, w1, true);
        ((int2*)nb8)[j] = make_int2(w0, w1);
    }
}

// ---------------- kernel 2: flash-LSE main (MX-fp8, K=128/instr) ----------------
// grid (128, 16): blockIdx.x = row block (BM=64), blockIdx.y = neg chunk (1024)
// v9: cross-tile LSE deferral, register-budgeted. Empirical gfx950 rule from
//     v4/v7/v8: arch-VGPR cap = 256/(waves per SIMD). Two acc sets need ~100
//     arch VGPRs -> (256,2) (cap 128). BM 128->64: each wave owns 16 q-rows,
//     acc set = 16 regs. Per iter: prefetch(t+1); ds_read+MFMA(t)->cur;
//     LSE(prev) [register-only, independent -> fills MFMA/LDS stall shadow];
//     barrier. LDS staging identical to v1. Straight-line macros, no lambdas.
__global__ __launch_bounds__(256, 2) void iw_main(
    const unsigned char* __restrict__ qb8, const unsigned char* __restrict__ nb8,
    float2* __restrict__ partial)
{
    constexpr int BM = 64, BN = 64;                           // 16 tiles of 64 negs
    __shared__ alignas(16) unsigned char n_lds[2 * BN * DIM]; // 2 x 8 KB

    const int tid  = threadIdx.x;
    const int lane = tid & 63;
    const int w    = tid >> 6;        // wave 0..3, owns 16 query rows
    const int quad = lane >> 4;
    const int c0   = lane & 15;

    const int row0   = blockIdx.x * BM;
    const int nbase0 = blockIdx.y * CHUNK;

    // ---- A fragment straight from global (fp8 row-major; 32 B/lane = K slice) ----
    U8 afrag;
    {
        const int qrow = row0 + w * 16 + c0;
        const int4* pa = reinterpret_cast<const int4*>(qb8 + (size_t)qrow * DIM + quad * 32);
        afrag.h[0] = pa[0];
        afrag.h[1] = pa[1];
    }

    // ---- staging offsets: granule (r, kbx) in LDS holds global chunk kbx^(r&3) ----
    int srcoff[2], dstoff[2];
#pragma unroll
    for (int j = 0; j < 2; ++j) {
        int L  = (w * 2 + j) * 64 + lane;   // 0..511
        int h  = L & 1, G = L >> 1;
        int r  = G >> 2;
        int kb = (G & 3) ^ (r & 3);
        srcoff[j] = r * DIM + kb * 32 + h * 16;
        dstoff[j] = (w * 2 + j) * 1024;     // wave-uniform dest base (+lane*16 by HW)
    }

    // B-read byte offset base: g0 = (c<<2)+(quad^(c&3)) with c = ns*16+c0.
    // (c&3)==(c0&3) -> quad^(c&3) is ns-independent; per-ns delta is 2048 B.
    const int bbase = ((c0 << 2) + (quad ^ (c0 & 3))) * 32;

    float m_s[4], l_s[4];
#pragma unroll
    for (int i = 0; i < 4; ++i) { m_s[i] = -1e30f; l_s[i] = 0.f; }

    const f32x4 zero4 = {0.f, 0.f, 0.f, 0.f};
    f32x4 accA[4], accB[4];

#define PREFETCH(T) do {                                                    \
    const unsigned char* _src = nb8 + (size_t)(nbase0 + (T) * BN) * DIM;    \
    unsigned char* _dst = n_lds + ((T) & 1) * (BN * DIM);                   \
    async_load16(_src + srcoff[0], _dst + dstoff[0]);                       \
    async_load16(_src + srcoff[1], _dst + dstoff[1]);                       \
} while (0)

#define COMPUTE(ACC, T) do {                                                \
    const unsigned char* _b = n_lds + ((T) & 1) * (BN * DIM) + bbase;       \
    U8 _b0, _b1, _b2, _b3;                                                  \
    { const int4* _p = reinterpret_cast<const int4*>(_b);                   \
      _b0.h[0] = _p[0]; _b0.h[1] = _p[1]; }                                 \
    { const int4* _p = reinterpret_cast<const int4*>(_b + 2048);            \
      _b1.h[0] = _p[0]; _b1.h[1] = _p[1]; }                                 \
    { const int4* _p = reinterpret_cast<const int4*>(_b + 4096);            \
      _b2.h[0] = _p[0]; _b2.h[1] = _p[1]; }                                 \
    { const int4* _p = reinterpret_cast<const int4*>(_b + 6144);            \
      _b3.h[0] = _p[0]; _b3.h[1] = _p[1]; }                                 \
    (ACC)[0] = __builtin_amdgcn_mfma_scale_f32_16x16x128_f8f6f4(            \
        afrag.v, _b0.v, zero4, 0, 0, 0, 127, 0, 127);                       \
    (ACC)[1] = __builtin_amdgcn_mfma_scale_f32_16x16x128_f8f6f4(            \
        afrag.v, _b1.v, zero4, 0, 0, 0, 127, 0, 127);                       \
    (ACC)[2] = __builtin_amdgcn_mfma_scale_f32_16x16x128_f8f6f4(            \
        afrag.v, _b2.v, zero4, 0, 0, 0, 127, 0, 127);                       \
    (ACC)[3] = __builtin_amdgcn_mfma_scale_f32_16x16x128_f8f6f4(            \
        afrag.v, _b3.v, zero4, 0, 0, 0, 127, 0, 127);                       \
} while (0)

#define LSE_UPDATE(ACC) do {                                                \
    _Pragma("unroll")                                                       \
    for (int i = 0; i < 4; ++i) {                                           \
        float y0 = (ACC)[0][i], y1 = (ACC)[1][i];                           \
        float y2 = (ACC)[2][i], y3 = (ACC)[3][i];                           \
        float m0 = m_s[i];                                                  \
        float nm = fmaxf(fmaxf(fmaxf(y2, y3), m0), fmaxf(y0, y1));          \
        float tt = fmaf(nm, -EXP_C, EXP_B);                                 \
        float e0 = fexp2(y0, tt), e1 = fexp2(y1, tt);                       \
        float e2 = fexp2(y2, tt), e3 = fexp2(y3, tt);                       \
        float er = fexp2(m0, tt);                                           \
        l_s[i] = fmaf(l_s[i], er, (e0 + e1) + (e2 + e3));                   \
        m_s[i] = nm;                                                        \
    }                                                                       \
} while (0)

    // prologue: stage tile 0, then compute it into accA (nothing to consume yet)
    PREFETCH(0);
    __syncthreads();
    PREFETCH(1);
    COMPUTE(accA, 0);
    __syncthreads();

    // steady state: tiles 1..14 in 7 pairs. LSE of tile t-1 (pure regs) issues
    // in the stall shadow of tile t's ds_read+MFMA. One barrier per tile.
    for (int p = 0; p < 7; ++p) {
        const int t1 = 2 * p + 1;
        PREFETCH(t1 + 1);
        COMPUTE(accB, t1);
        LSE_UPDATE(accA);
        __syncthreads();

        PREFETCH(t1 + 2);
        COMPUTE(accA, t1 + 1);
        LSE_UPDATE(accB);
        __syncthreads();
    }

    // tail: tile 15 -> accB, consume accA, then drain accB (no barrier needed)
    COMPUTE(accB, 15);
    LSE_UPDATE(accA);
    LSE_UPDATE(accB);

#undef PREFETCH
#undef COMPUTE
#undef LSE_UPDATE

    // ---- merge (m,l) across the 16 lanes of each quad-row group (exact exp2) ----
#pragma unroll
    for (int i = 0; i < 4; ++i) {
        float m = m_s[i], l = l_s[i];
#pragma unroll
        for (int s = 1; s < 16; s <<= 1) {
            float om = __shfl_xor(m, s, 64);
            float ol = __shfl_xor(l, s, 64);
            float nm = fmaxf(m, om);
            l = l * __builtin_amdgcn_exp2f(m - nm) + ol * __builtin_amdgcn_exp2f(om - nm);
            m = nm;
        }
        if (c0 == 0) {
            int grow = row0 + w * 16 + quad * 4 + i;
            partial[(size_t)blockIdx.y * NQ + grow] = make_float2(m, l);
        }
    }
}

// ---------------- kernel 3: merge chunks + mean reduce ----------------
__global__ __launch_bounds__(256) void iw_merge(
    const float2* __restrict__ partial, float* __restrict__ out)
{
    const int tid = threadIdx.x;
    const int row = blockIdx.x * 256 + tid;   // 32 blocks * 256 = 8192
    float M = -1e30f, L = 0.f;
#pragma unroll
    for (int c = 0; c < SPLIT; ++c) {
        float2 p = partial[(size_t)c * NQ + row];
        float nm = fmaxf(M, p.x);
        L = L * __builtin_amdgcn_exp2f(M - nm) + p.y * __builtin_amdgcn_exp2f(p.x - nm);
        M = nm;
    }
    float lse = LN2 * (M + __log2f(L));       // natural-log LSE of scores/tau
    float v = lse * (1.0f / (float)NQ);
    v = waveReduceSum(v);
    __shared__ float red[4];
    if ((tid & 63) == 0) red[tid >> 6] = v;
    __syncthreads();
    if (tid == 0) atomicAdd(out, red[0] + red[1] + red[2] + red[3]);
}

// ---------------- launch ----------------
extern "C" void kernel_launch(void* const* d_in, const int* in_sizes, int n_in,
                              void* d_out, int out_size, void* d_ws, size_t ws_size,
                              hipStream_t stream) {
    const float* q   = (const float*)d_in[0];
    const float* pos = (const float*)d_in[1];
    const float* neg = (const float*)d_in[2];
    float* out = (float*)d_out;

    unsigned char* qb8 = (unsigned char*)d_ws;                     // 1 MB
    unsigned char* nb8 = qb8 + (size_t)NQ * DIM;                   // 2 MB
    float2* partial    = (float2*)(nb8 + (size_t)NNEG * DIM);      // 1 MB

    hipMemsetAsync(out, 0, sizeof(float), stream);
    iw_prep <<<1536, 256, 0, stream>>>(q, pos, neg, qb8, nb8, out);
    iw_main <<<dim3(NQ / 64, SPLIT), 256, 0, stream>>>(qb8, nb8, partial);
    iw_merge<<<32,   256, 0, stream>>>(partial, out);
}